// Round 9
// baseline (401.193 us; speedup 1.0000x reference)
//
#include <hip/hip_runtime.h>
#include <math.h>

#define NN 100000
#define NE 1600000
#define IN_DIM 256
#define HD 128           // HEADS*OUT_DIM
#define NEG_SLOPE 0.2f

#define B1SH 9                         // 512 nodes per coarse bucket
#define NPB (1 << B1SH)                // 512
#define NB1 ((NN + NPB - 1) / NPB)     // 196 coarse buckets
#define SC_BLOCKS ((NE / 4 + 1023) / 1024)   // 391 blocks, 4096 edges each
#define SCP 392                        // padded row stride (mult of 4, SC_BLOCKS+1)
#define NGB 256                        // gemm-role blocks (8 waves each, grid-stride)
#define NGROUPS (NN / 16)              // 6250 row-groups of 16 (exact)
#define D2_GRID (SC_BLOCKS + NGB)

typedef __attribute__((ext_vector_type(8))) __bf16 bf16x8;
typedef __attribute__((ext_vector_type(4))) float floatx4;
typedef __attribute__((ext_vector_type(2))) float f32x2;

__device__ inline unsigned short f2bf(float f) {
    unsigned int b = __float_as_uint(f);
    b += 0x7fffu + ((b >> 16) & 1u);   // round-to-nearest-even
    return (unsigned short)(b >> 16);
}
__device__ inline unsigned int pk(float lo, float hi) {
    return (unsigned int)f2bf(lo) | ((unsigned int)f2bf(hi) << 16);
}
__device__ inline float lrelu(float v) { return (v > 0.f) ? v : v * NEG_SLOPE; }
__device__ inline f32x2 un2(unsigned int v) {
    f32x2 r;
    r.x = __uint_as_float(v << 16);
    r.y = __uint_as_float(v & 0xffff0000u);
    return r;
}

// ================= D1: precount (blocks 0..390)  ||  prep_w (391..406) ======
// precount writes its histogram row TRANSPOSED: gcnt2dT[bucket*SCP + block],
// so D2's prefix pass reads contiguous rows. Block 0 zeroes the pad column.
__global__ __launch_bounds__(256) void d1_kernel(const float* __restrict__ W,
                                                 unsigned int* __restrict__ wswz,
                                                 const int4* __restrict__ dst4,
                                                 int* __restrict__ gcnt2dT) {
    __shared__ int cnt[NB1];
    const int t = threadIdx.x;
    if (blockIdx.x < SC_BLOCKS) {
        // ---- precount role ----
        for (int i = t; i < NB1; i += 256) cnt[i] = 0;
        __syncthreads();
        int base4 = blockIdx.x * 1024;
#pragma unroll
        for (int k = 0; k < 4; ++k) {
            int gi = base4 + k * 256 + t;
            if (gi < NE / 4) {
                int4 d = dst4[gi];
                atomicAdd(&cnt[d.x >> B1SH], 1);
                atomicAdd(&cnt[d.y >> B1SH], 1);
                atomicAdd(&cnt[d.z >> B1SH], 1);
                atomicAdd(&cnt[d.w >> B1SH], 1);
            }
        }
        __syncthreads();
        for (int i = t; i < NB1; i += 256)
            gcnt2dT[i * SCP + blockIdx.x] = cnt[i];
        if (blockIdx.x == 0)
            for (int i = t; i < NB1; i += 256)
                gcnt2dT[i * SCP + SC_BLOCKS] = 0;   // pad column
    } else {
        // ---- prep_w role: swizzle W[256][128] fp32 -> bf16 B-fragments ----
        int g = (blockIdx.x - SC_BLOCKS) * 256 + t;   // 0..4095
        int lane = g & 63;
        int tt = (g >> 6) & 7;
        int c = g >> 9;
        int sub = lane & 15, quad = lane >> 4;
        int n = tt * 16 + sub;
        int kbase = c * 32 + quad * 8;
        unsigned int ob = (unsigned int)g * 4;
#pragma unroll
        for (int i = 0; i < 4; ++i) {
            float lo = W[(size_t)(kbase + 2 * i) * HD + n];
            float hi = W[(size_t)(kbase + 2 * i + 1) * HD + n];
            wswz[ob + i] = pk(lo, hi);
        }
    }
}

// ========== D2 (512 threads): scatter (blocks 0..390) || gemm (391..646) ====
// Range split: scatter blocks drain early, gemm backfills.
// gemm role: 8 waves share ONE 64 KB LDS staging of wswz -> 2 blocks/CU =
// 16 waves/CU = 4 waves/SIMD (launch_bounds(512,4) pins VGPR<=128).
// x-loads issued in two 8-load halves (short live ranges, round-1 pattern).
__global__ __launch_bounds__(512, 4) void d2_kernel(const float* __restrict__ x,
                                                    const uint4* __restrict__ wswz,
                                                    const float* __restrict__ attn_l,
                                                    const float* __restrict__ attn_r,
                                                    unsigned short* __restrict__ featb,
                                                    float* __restrict__ el,
                                                    float* __restrict__ er,
                                                    const int4* __restrict__ src4,
                                                    const int4* __restrict__ dst4,
                                                    const int* __restrict__ gcnt2dT,
                                                    unsigned int* __restrict__ pkd,
                                                    int* __restrict__ regstart) {
    __shared__ uint4 smem[4096];                  // 64 KB: B-frags (gemm) / scratch (scatter)
    const int t = threadIdx.x;
    const int bid = blockIdx.x;

    if (bid < SC_BLOCKS) {
        // ---- scatter role (512 threads, 8 edges/thread) ----
        int* cnt   = (int*)smem;                  // [NB1]
        int* gbase = cnt + NB1;                   // [NB1]
        int* sh    = gbase + NB1;                 // [512]
        const int b = bid;
        // prefix over transposed counts: contiguous int4 row reads
        int colsum = 0, mypre = 0;
        if (t < NB1) {
            const int4* rowp = (const int4*)(gcnt2dT + t * SCP);
#pragma unroll 7
            for (int q = 0; q < SCP / 4; ++q) {   // 98 int4 loads
                int4 v = rowp[q];
                int s4 = v.x + v.y + v.z + v.w;
                colsum += s4;
                int base = q * 4;
                if (base + 4 <= b) {
                    mypre += s4;
                } else {
                    if (base + 0 < b) mypre += v.x;
                    if (base + 1 < b) mypre += v.y;
                    if (base + 2 < b) mypre += v.z;
                    if (base + 3 < b) mypre += v.w;
                }
            }
        }
        sh[t] = (t < NB1) ? colsum : 0;
        __syncthreads();
        for (int o = 1; o < 512; o <<= 1) {
            int a = (t >= o) ? sh[t - o] : 0;
            __syncthreads();
            sh[t] += a;
            __syncthreads();
        }
        int rstart = sh[t] - ((t < NB1) ? colsum : 0);   // exclusive scan
        if (t < NB1) gbase[t] = rstart + mypre;
        if (b == 0 && t < NB1) regstart[t] = rstart;
        if (b == 0 && t == 0) regstart[NB1] = NE;
        for (int i = t; i < NB1; i += 512) cnt[i] = 0;
        __syncthreads();

        int base4 = b * 1024;
        unsigned int pkv[8];
        unsigned int brk[8];
#pragma unroll
        for (int k = 0; k < 2; ++k) {
            int gi = base4 + k * 512 + t;
            bool ok = gi < NE / 4;
            int gic = ok ? gi : 0;
            int4 s = src4[gic];
            int4 d = dst4[gic];
            int dd[4] = {d.x, d.y, d.z, d.w};
            int ss[4] = {s.x, s.y, s.z, s.w};
#pragma unroll
            for (int j4 = 0; j4 < 4; ++j4) {
                int e = k * 4 + j4;
                if (ok) {
                    int bk = dd[j4] >> B1SH;
                    int r = atomicAdd(&cnt[bk], 1);                      // local rank
                    brk[e] = ((unsigned int)bk << 12) | (unsigned int)r; // r < 4096
                    pkv[e] = ((unsigned int)(dd[j4] & (NPB - 1)) << 17) | (unsigned int)ss[j4];
                } else {
                    brk[e] = 0xFFFFFFFFu;
                }
            }
        }
        __syncthreads();
#pragma unroll
        for (int e = 0; e < 8; ++e) {
            if (brk[e] != 0xFFFFFFFFu) {
                int bk = brk[e] >> 12;
                int r = brk[e] & 0xFFF;
                pkd[gbase[bk] + r] = pkv[e];
            }
        }
    } else {
        // ---- gemm role (MFMA, wswz staged in LDS shared by 8 waves) ----
        const int gb = bid - SC_BLOCKS;           // 0..NGB-1
        // stage 64 KB of B-fragments: 8 iters x 512 threads x 16 B
#pragma unroll
        for (int i = 0; i < 8; ++i)
            smem[i * 512 + t] = wswz[i * 512 + t];
        __syncthreads();

        const int lane = t & 63, wv = t >> 6;     // wv in 0..7
        const int sub = lane & 15, quad = lane >> 4;

        float al[8], ar[8];
#pragma unroll
        for (int tt = 0; tt < 8; ++tt) {
            al[tt] = attn_l[tt * 16 + sub];
            ar[tt] = attn_r[tt * 16 + sub];
        }

        for (int gg = gb * 8 + wv; gg < NGROUPS; gg += NGB * 8) {
            const int row0 = gg * 16;             // rows row0..row0+15 (always < NN)
            const float* xp = x + (size_t)(row0 + sub) * IN_DIM + quad * 8;

            // two 8-load halves with short live ranges (bounds VGPR)
            bf16x8 af[8];
#pragma unroll
            for (int h = 0; h < 2; ++h) {
                float4 raw[4][2];
#pragma unroll
                for (int c = 0; c < 4; ++c) {
                    raw[c][0] = *(const float4*)(xp + (h * 4 + c) * 32);
                    raw[c][1] = *(const float4*)(xp + (h * 4 + c) * 32 + 4);
                }
#pragma unroll
                for (int c = 0; c < 4; ++c) {
                    uint4 au;
                    au.x = pk(raw[c][0].x, raw[c][0].y);
                    au.y = pk(raw[c][0].z, raw[c][0].w);
                    au.z = pk(raw[c][1].x, raw[c][1].y);
                    au.w = pk(raw[c][1].z, raw[c][1].w);
                    af[h * 4 + c] = __builtin_bit_cast(bf16x8, au);
                }
            }

            floatx4 acc[8];
#pragma unroll
            for (int tt = 0; tt < 8; ++tt) acc[tt] = (floatx4){0.f, 0.f, 0.f, 0.f};

#pragma unroll
            for (int c = 0; c < 8; ++c) {
#pragma unroll
                for (int tt = 0; tt < 8; ++tt) {
                    bf16x8 bfr = __builtin_bit_cast(bf16x8, smem[(c * 8 + tt) * 64 + lane]);
                    acc[tt] = __builtin_amdgcn_mfma_f32_16x16x32_bf16(af[c], bfr, acc[tt], 0, 0, 0);
                }
            }

#pragma unroll
            for (int r = 0; r < 4; ++r) {
                int row = row0 + quad * 4 + r;    // C/D: row = quad*4 + reg
                uint4 fv;
                fv.x = pk(acc[0][r], acc[1][r]);
                fv.y = pk(acc[2][r], acc[3][r]);
                fv.z = pk(acc[4][r], acc[5][r]);
                fv.w = pk(acc[6][r], acc[7][r]);
                float pl[4], pr[4];
#pragma unroll
                for (int hh = 0; hh < 4; ++hh) {
                    pl[hh] = acc[2 * hh][r] * al[2 * hh] + acc[2 * hh + 1][r] * al[2 * hh + 1];
                    pr[hh] = acc[2 * hh][r] * ar[2 * hh] + acc[2 * hh + 1][r] * ar[2 * hh + 1];
                }
#pragma unroll
                for (int o = 1; o < 16; o <<= 1) {
#pragma unroll
                    for (int hh = 0; hh < 4; ++hh) {
                        pl[hh] += __shfl_xor(pl[hh], o);
                        pr[hh] += __shfl_xor(pr[hh], o);
                    }
                }
                *(uint4*)(featb + (size_t)row * HD + sub * 8) = fv;
                if (sub < 4) {
                    float vl = (sub == 0) ? pl[0] : (sub == 1) ? pl[1] : (sub == 2) ? pl[2] : pl[3];
                    float vr = (sub == 0) ? pr[0] : (sub == 1) ? pr[1] : (sub == 2) ? pr[2] : pr[3];
                    el[row * 4 + sub] = vl;
                    er[row * 4 + sub] = vr;
                }
            }
        }
    }
}

// ====== D3: build (1024 threads/block): fine histogram -> offs, place ======
__global__ __launch_bounds__(1024) void build_kernel(const unsigned int* __restrict__ pkd,
                                                     const int* __restrict__ regstart,
                                                     int* __restrict__ offs,
                                                     int* __restrict__ csr_src) {
    __shared__ int fcnt[NPB];
    __shared__ int foffs[NPB];
    __shared__ int ssc[NPB];
    int b = blockIdx.x, t = threadIdx.x;     // t < 1024
    int rs = regstart[b], re = regstart[b + 1];
    int n = re - rs;
    if (b == 0 && t == 0) offs[NN] = NE;

    if (t < NPB) fcnt[t] = 0;
    __syncthreads();
    for (int i = t; i < n; i += 1024) {
        unsigned int v = pkd[rs + i];
        atomicAdd(&fcnt[v >> 17], 1);
    }
    __syncthreads();
    // exclusive scan of 512 counts (threads 0..511)
    int a = 0;
    if (t < NPB) { a = fcnt[t]; ssc[t] = a; }
    __syncthreads();
    for (int o = 1; o < NPB; o <<= 1) {
        int u = 0;
        if (t < NPB && t >= o) u = ssc[t - o];
        __syncthreads();
        if (t < NPB) ssc[t] += u;
        __syncthreads();
    }
    if (t < NPB) {
        foffs[t] = ssc[t] - a;
        int node = b * NPB + t;
        if (node < NN) offs[node] = rs + foffs[t];
        fcnt[t] = 0;                         // reuse as cursors
    }
    __syncthreads();
    // placement pass, 4x unrolled, stride 1024
    int i = t;
    for (; i + 3072 < n; i += 4096) {
        unsigned int v0 = pkd[rs + i];
        unsigned int v1 = pkd[rs + i + 1024];
        unsigned int v2 = pkd[rs + i + 2048];
        unsigned int v3 = pkd[rs + i + 3072];
        int j0 = v0 >> 17, j1 = v1 >> 17, j2 = v2 >> 17, j3 = v3 >> 17;
        int r0 = atomicAdd(&fcnt[j0], 1);
        int r1 = atomicAdd(&fcnt[j1], 1);
        int r2 = atomicAdd(&fcnt[j2], 1);
        int r3 = atomicAdd(&fcnt[j3], 1);
        csr_src[rs + foffs[j0] + r0] = (int)(v0 & 0x1FFFFu);
        csr_src[rs + foffs[j1] + r1] = (int)(v1 & 0x1FFFFu);
        csr_src[rs + foffs[j2] + r2] = (int)(v2 & 0x1FFFFu);
        csr_src[rs + foffs[j3] + r3] = (int)(v3 & 0x1FFFFu);
    }
    for (; i < n; i += 1024) {
        unsigned int v = pkd[rs + i];
        int j = v >> 17;
        int r = atomicAdd(&fcnt[j], 1);
        csr_src[rs + foffs[j] + r] = (int)(v & 0x1FFFFu);
    }
}

// ====== D4: softmax + aggregation (at fabric random-gather ceiling) =========
#define CH 32
__global__ __launch_bounds__(256, 4) void aggregate_kernel(const uint4* __restrict__ featu4,
                                                           const float4* __restrict__ el4,
                                                           const float4* __restrict__ er4,
                                                           const int* __restrict__ offs,
                                                           const int* __restrict__ csr_src,
                                                           float* __restrict__ out) {
    __shared__ int    s_sv[4][4][CH + 1];
    __shared__ float4 s_a4[4][4][CH + 1];
    __shared__ int sdeg[16], smap[16];

    const int tid = threadIdx.x;
    const int lane = tid & 63, wv = tid >> 6;
    const int g = lane >> 4, sub = lane & 15;

    // within-block degree sort of the 16 nodes (O(16^2) rank compare)
    if (tid < 16) {
        int n0 = blockIdx.x * 16 + tid;            // NN == 6250*16 exactly
        sdeg[tid] = offs[n0 + 1] - offs[n0];
    }
    __syncthreads();
    if (tid < 16) {
        int d = sdeg[tid];
        int rank = 0;
#pragma unroll
        for (int j = 0; j < 16; ++j) {
            int dj = sdeg[j];
            rank += (dj < d) || (dj == d && j < tid);
        }
        smap[rank] = blockIdx.x * 16 + tid;
    }
    __syncthreads();
    const int node = smap[wv * 4 + g];
    const int beg = offs[node], end = offs[node + 1];

    const float4 erv = er4[node];
    float4 sm = make_float4(0.f, 0.f, 0.f, 0.f);
    f32x2 acc2[4];
#pragma unroll
    for (int i = 0; i < 4; ++i) acc2[i] = (f32x2){0.f, 0.f};

    for (int c0 = beg; c0 < end; c0 += CH) {
        int cnt = end - c0;
        if (cnt > CH) cnt = CH;

        // phase 1: indices -> LDS (pre-scaled by 16 for featu4 addressing)
        int svr[2];
#pragma unroll
        for (int t = 0; t < 2; ++t) {
            int slot = sub + t * 16;
            int sv = (slot < cnt) ? csr_src[c0 + slot] : 0;
            svr[t] = sv;
            s_sv[wv][g][slot] = sv * 16;
        }

        // phase 2: prologue — issue round-0 gather loads now
        uint4 ua[8], ub[8];
#pragma unroll
        for (int e = 0; e < 8; ++e)
            ua[e] = featu4[(size_t)s_sv[wv][g][e] + sub];

        // phase 3: weights (expf chain hides under the round-0 loads)
#pragma unroll
        for (int t = 0; t < 2; ++t) {
            int slot = sub + t * 16;
            float4 w = make_float4(0.f, 0.f, 0.f, 0.f);
            if (slot < cnt) {
                float4 e = el4[svr[t]];
                w.x = __expf(lrelu(e.x + erv.x));
                w.y = __expf(lrelu(e.y + erv.y));
                w.z = __expf(lrelu(e.z + erv.z));
                w.w = __expf(lrelu(e.w + erv.w));
                sm.x += w.x; sm.y += w.y; sm.z += w.z; sm.w += w.w;
            }
            s_a4[wv][g][slot] = w;
        }

        int rounds = (cnt + 7) >> 3;
        int jr = 0;
        while (true) {
            bool m1 = (jr + 1) < rounds;
            if (m1) {
                int nb = (jr + 1) << 3;
#pragma unroll
                for (int e = 0; e < 8; ++e)
                    ub[e] = featu4[(size_t)s_sv[wv][g][nb + e] + sub];
            }
            {
                int jb = jr << 3;
#pragma unroll
                for (int e = 0; e < 8; ++e) {
                    float4 we = s_a4[wv][g][jb + e];
                    uint4 u = ua[e];
                    f32x2 w0 = {we.x, we.x}, w1 = {we.y, we.y};
                    f32x2 w2 = {we.z, we.z}, w3 = {we.w, we.w};
                    acc2[0] = __builtin_elementwise_fma(w0, un2(u.x), acc2[0]);
                    acc2[1] = __builtin_elementwise_fma(w1, un2(u.y), acc2[1]);
                    acc2[2] = __builtin_elementwise_fma(w2, un2(u.z), acc2[2]);
                    acc2[3] = __builtin_elementwise_fma(w3, un2(u.w), acc2[3]);
                }
            }
            ++jr;
            if (!m1) break;
            bool m2 = (jr + 1) < rounds;
            if (m2) {
                int nb = (jr + 1) << 3;
#pragma unroll
                for (int e = 0; e < 8; ++e)
                    ua[e] = featu4[(size_t)s_sv[wv][g][nb + e] + sub];
            }
            {
                int jb = jr << 3;
#pragma unroll
                for (int e = 0; e < 8; ++e) {
                    float4 we = s_a4[wv][g][jb + e];
                    uint4 u = ub[e];
                    f32x2 w0 = {we.x, we.x}, w1 = {we.y, we.y};
                    f32x2 w2 = {we.z, we.z}, w3 = {we.w, we.w};
                    acc2[0] = __builtin_elementwise_fma(w0, un2(u.x), acc2[0]);
                    acc2[1] = __builtin_elementwise_fma(w1, un2(u.y), acc2[1]);
                    acc2[2] = __builtin_elementwise_fma(w2, un2(u.z), acc2[2]);
                    acc2[3] = __builtin_elementwise_fma(w3, un2(u.w), acc2[3]);
                }
            }
            ++jr;
            if (!m2) break;
        }
    }

    // reduce denominators across the 16 lanes of this node
#pragma unroll
    for (int o = 1; o < 16; o <<= 1) {
        sm.x += __shfl_xor(sm.x, o);
        sm.y += __shfl_xor(sm.y, o);
        sm.z += __shfl_xor(sm.z, o);
        sm.w += __shfl_xor(sm.w, o);
    }
    float ix = 1.f / fmaxf(sm.x, 1e-9f);
    float iy = 1.f / fmaxf(sm.y, 1e-9f);
    float iz = 1.f / fmaxf(sm.z, 1e-9f);
    float iw = 1.f / fmaxf(sm.w, 1e-9f);
    float ox = 0.25f * (acc2[0].x * ix + acc2[1].x * iy + acc2[2].x * iz + acc2[3].x * iw);
    float oy = 0.25f * (acc2[0].y * ix + acc2[1].y * iy + acc2[2].y * iz + acc2[3].y * iw);
    out[node * 32 + sub]      = ox;
    out[node * 32 + 16 + sub] = oy;
}

// ---------------- launch ----------------
extern "C" void kernel_launch(void* const* d_in, const int* in_sizes, int n_in,
                              void* d_out, int out_size, void* d_ws, size_t ws_size,
                              hipStream_t stream) {
    const float* x      = (const float*)d_in[0];
    const float* W      = (const float*)d_in[1];
    const float* attn_l = (const float*)d_in[2];
    const float* attn_r = (const float*)d_in[3];
    const int*   src    = (const int*)d_in[4];
    const int*   dst    = (const int*)d_in[5];
    float* out = (float*)d_out;

    char* p = (char*)d_ws;
    auto alloc = [&](size_t bytes) -> void* {
        void* r = (void*)p;
        p += (bytes + 255) & ~(size_t)255;
        return r;
    };
    unsigned short* featb = (unsigned short*)alloc((size_t)NN * HD * 2);
    unsigned int*   wswz  = (unsigned int*)alloc(4096 * 16);
    float* el      = (float*)alloc((size_t)NN * 4 * 4);
    float* er      = (float*)alloc((size_t)NN * 4 * 4);
    int*   offs    = (int*)alloc((size_t)(NN + 1) * 4);
    unsigned int* pkd = (unsigned int*)alloc((size_t)NE * 4);
    int*   csr     = (int*)alloc((size_t)NE * 4);
    int*   gcnt2dT = (int*)alloc((size_t)NB1 * SCP * 4);
    int*   regstart= (int*)alloc((size_t)(NB1 + 1) * 4);

    d1_kernel<<<SC_BLOCKS + 16, 256, 0, stream>>>(W, wswz, (const int4*)dst, gcnt2dT);
    d2_kernel<<<D2_GRID, 512, 0, stream>>>(x, (const uint4*)wswz, attn_l, attn_r,
                                           featb, el, er,
                                           (const int4*)src, (const int4*)dst,
                                           gcnt2dT, pkd, regstart);
    build_kernel<<<NB1, 1024, 0, stream>>>(pkd, regstart, offs, csr);
    aggregate_kernel<<<NN / 16, 256, 0, stream>>>((const uint4*)featb, (const float4*)el,
                                                  (const float4*)er, offs, csr, out);
}

// Round 11
// 294.622 us; speedup vs baseline: 1.3617x; 1.3617x over previous
//
#include <hip/hip_runtime.h>
#include <math.h>

#define NN 100000
#define NE 1600000
#define IN_DIM 256
#define HD 128           // HEADS*OUT_DIM
#define NEG_SLOPE 0.2f

#define B1SH 9                         // 512 nodes per coarse bucket
#define NPB (1 << B1SH)                // 512
#define NB1 ((NN + NPB - 1) / NPB)     // 196 coarse buckets
#define SC_BLOCKS ((NE / 4 + 1023) / 1024)   // 391 blocks, 4096 edges each
#define SCP 392                        // padded row stride (mult of 4, SC_BLOCKS+1)
#define GEMM_BLOCKS ((NN + 63) / 64)   // 1563
#define D2_GRID (SC_BLOCKS + GEMM_BLOCKS)

typedef __attribute__((ext_vector_type(8))) __bf16 bf16x8;
typedef __attribute__((ext_vector_type(4))) float floatx4;
typedef __attribute__((ext_vector_type(2))) float f32x2;

__device__ inline unsigned short f2bf(float f) {
    unsigned int b = __float_as_uint(f);
    b += 0x7fffu + ((b >> 16) & 1u);   // round-to-nearest-even
    return (unsigned short)(b >> 16);
}
__device__ inline unsigned int pk(float lo, float hi) {
    return (unsigned int)f2bf(lo) | ((unsigned int)f2bf(hi) << 16);
}
__device__ inline float lrelu(float v) { return (v > 0.f) ? v : v * NEG_SLOPE; }
__device__ inline f32x2 un2(unsigned int v) {
    f32x2 r;
    r.x = __uint_as_float(v << 16);
    r.y = __uint_as_float(v & 0xffff0000u);
    return r;
}

// ================= D1: precount (blocks 0..390)  ||  prep_w (391..406) ======
// precount writes its histogram row TRANSPOSED: gcnt2dT[bucket*SCP + block],
// so D2's prefix pass reads contiguous rows. Block 0 zeroes the pad column.
__global__ __launch_bounds__(256) void d1_kernel(const float* __restrict__ W,
                                                 unsigned int* __restrict__ wswz,
                                                 const int4* __restrict__ dst4,
                                                 int* __restrict__ gcnt2dT) {
    __shared__ int cnt[NB1];
    const int t = threadIdx.x;
    if (blockIdx.x < SC_BLOCKS) {
        // ---- precount role ----
        for (int i = t; i < NB1; i += 256) cnt[i] = 0;
        __syncthreads();
        int base4 = blockIdx.x * 1024;
#pragma unroll
        for (int k = 0; k < 4; ++k) {
            int gi = base4 + k * 256 + t;
            if (gi < NE / 4) {
                int4 d = dst4[gi];
                atomicAdd(&cnt[d.x >> B1SH], 1);
                atomicAdd(&cnt[d.y >> B1SH], 1);
                atomicAdd(&cnt[d.z >> B1SH], 1);
                atomicAdd(&cnt[d.w >> B1SH], 1);
            }
        }
        __syncthreads();
        for (int i = t; i < NB1; i += 256)
            gcnt2dT[i * SCP + blockIdx.x] = cnt[i];
        if (blockIdx.x == 0)
            for (int i = t; i < NB1; i += 256)
                gcnt2dT[i * SCP + SC_BLOCKS] = 0;   // pad column
    } else {
        // ---- prep_w role: swizzle W[256][128] fp32 -> bf16 B-fragments ----
        int g = (blockIdx.x - SC_BLOCKS) * 256 + t;   // 0..4095
        int lane = g & 63;
        int tt = (g >> 6) & 7;
        int c = g >> 9;
        int sub = lane & 15, quad = lane >> 4;
        int n = tt * 16 + sub;
        int kbase = c * 32 + quad * 8;
        unsigned int ob = (unsigned int)g * 4;
#pragma unroll
        for (int i = 0; i < 4; ++i) {
            float lo = W[(size_t)(kbase + 2 * i) * HD + n];
            float hi = W[(size_t)(kbase + 2 * i + 1) * HD + n];
            wswz[ob + i] = pk(lo, hi);
        }
    }
}

// ====== D2 (256 threads): scatter (blocks 0..390) || gemm (391..1953) =======
// Round-6 measured-best shape: range split, dense block->row mapping, no LDS
// in the gemm role (wswz B-fragments read from L2; 64 KB, XCD-resident).
// Only delta vs round 6: the scatter prefix uses the transposed count matrix
// (98 contiguous int4 reads instead of 391 stride-784 scalars).
__global__ __launch_bounds__(256) void d2_kernel(const float* __restrict__ x,
                                                 const uint4* __restrict__ wswz,
                                                 const float* __restrict__ attn_l,
                                                 const float* __restrict__ attn_r,
                                                 unsigned short* __restrict__ featb,
                                                 float* __restrict__ el,
                                                 float* __restrict__ er,
                                                 const int4* __restrict__ src4,
                                                 const int4* __restrict__ dst4,
                                                 const int* __restrict__ gcnt2dT,
                                                 unsigned int* __restrict__ pkd,
                                                 int* __restrict__ regstart) {
    __shared__ int cnt[NB1];
    __shared__ int gbase[NB1];
    __shared__ int sh[256];
    const int t = threadIdx.x;
    const int bid = blockIdx.x;

    if (bid < SC_BLOCKS) {
        // ---- scatter role ----
        const int b = bid;
        // prefix over transposed counts: contiguous int4 row reads
        int colsum = 0, mypre = 0;
        if (t < NB1) {
            const int4* rowp = (const int4*)(gcnt2dT + t * SCP);
#pragma unroll 7
            for (int q = 0; q < SCP / 4; ++q) {   // 98 int4 loads
                int4 v = rowp[q];
                int s4 = v.x + v.y + v.z + v.w;
                colsum += s4;
                int base = q * 4;
                if (base + 4 <= b) {
                    mypre += s4;
                } else {
                    if (base + 0 < b) mypre += v.x;
                    if (base + 1 < b) mypre += v.y;
                    if (base + 2 < b) mypre += v.z;
                    if (base + 3 < b) mypre += v.w;
                }
            }
        }
        sh[t] = (t < NB1) ? colsum : 0;
        __syncthreads();
        for (int o = 1; o < 256; o <<= 1) {
            int a = (t >= o) ? sh[t - o] : 0;
            __syncthreads();
            sh[t] += a;
            __syncthreads();
        }
        int rstart = sh[t] - ((t < NB1) ? colsum : 0);   // exclusive scan
        if (t < NB1) gbase[t] = rstart + mypre;
        if (b == 0 && t < NB1) regstart[t] = rstart;
        if (b == 0 && t == 0) regstart[NB1] = NE;
        for (int i = t; i < NB1; i += 256) cnt[i] = 0;
        __syncthreads();

        int base4 = b * 1024;
        unsigned int pkv[16];
        unsigned int brk[16];
#pragma unroll
        for (int k = 0; k < 4; ++k) {
            int gi = base4 + k * 256 + t;
            bool ok = gi < NE / 4;
            int gic = ok ? gi : 0;
            int4 s = src4[gic];
            int4 d = dst4[gic];
            int dd[4] = {d.x, d.y, d.z, d.w};
            int ss[4] = {s.x, s.y, s.z, s.w};
#pragma unroll
            for (int j4 = 0; j4 < 4; ++j4) {
                int e = k * 4 + j4;
                if (ok) {
                    int bk = dd[j4] >> B1SH;
                    int r = atomicAdd(&cnt[bk], 1);                      // local rank
                    brk[e] = ((unsigned int)bk << 12) | (unsigned int)r; // r < 4096
                    pkv[e] = ((unsigned int)(dd[j4] & (NPB - 1)) << 17) | (unsigned int)ss[j4];
                } else {
                    brk[e] = 0xFFFFFFFFu;
                }
            }
        }
        __syncthreads();
#pragma unroll
        for (int e = 0; e < 16; ++e) {
            if (brk[e] != 0xFFFFFFFFu) {
                int bk = brk[e] >> 12;
                int r = brk[e] & 0xFFF;
                pkd[gbase[bk] + r] = pkv[e];
            }
        }
    } else {
        // ---- gemm role (MFMA, no LDS, dense block->row mapping) ----
        const int gb = bid - SC_BLOCKS;           // 0..GEMM_BLOCKS-1
        const int lane = t & 63, wv = t >> 6;
        const int sub = lane & 15, quad = lane >> 4;
        const int row0 = gb * 64 + wv * 16;

        int m = row0 + sub;
        if (m >= NN) m = NN - 1;                 // clamp loads; stores guarded
        const float* xp = x + (size_t)m * IN_DIM + quad * 8;

        bf16x8 af[8];
#pragma unroll
        for (int h = 0; h < 2; ++h) {
            float4 raw[4][2];
#pragma unroll
            for (int c = 0; c < 4; ++c) {
                raw[c][0] = *(const float4*)(xp + (h * 4 + c) * 32);
                raw[c][1] = *(const float4*)(xp + (h * 4 + c) * 32 + 4);
            }
#pragma unroll
            for (int c = 0; c < 4; ++c) {
                uint4 au;
                au.x = pk(raw[c][0].x, raw[c][0].y);
                au.y = pk(raw[c][0].z, raw[c][0].w);
                au.z = pk(raw[c][1].x, raw[c][1].y);
                au.w = pk(raw[c][1].z, raw[c][1].w);
                af[h * 4 + c] = __builtin_bit_cast(bf16x8, au);
            }
        }

        floatx4 acc[8];
#pragma unroll
        for (int tt = 0; tt < 8; ++tt) acc[tt] = (floatx4){0.f, 0.f, 0.f, 0.f};

#pragma unroll
        for (int c = 0; c < 8; ++c) {
            uint4 bu[8];
#pragma unroll
            for (int tt = 0; tt < 8; ++tt) bu[tt] = wswz[(c * 8 + tt) * 64 + lane];
#pragma unroll
            for (int tt = 0; tt < 8; ++tt) {
                bf16x8 bfr = __builtin_bit_cast(bf16x8, bu[tt]);
                acc[tt] = __builtin_amdgcn_mfma_f32_16x16x32_bf16(af[c], bfr, acc[tt], 0, 0, 0);
            }
        }

        float al[8], ar[8];
#pragma unroll
        for (int tt = 0; tt < 8; ++tt) {
            al[tt] = attn_l[tt * 16 + sub];
            ar[tt] = attn_r[tt * 16 + sub];
        }

#pragma unroll
        for (int r = 0; r < 4; ++r) {
            int row = row0 + quad * 4 + r;       // C/D: row = quad*4 + reg
            uint4 fv;
            fv.x = pk(acc[0][r], acc[1][r]);
            fv.y = pk(acc[2][r], acc[3][r]);
            fv.z = pk(acc[4][r], acc[5][r]);
            fv.w = pk(acc[6][r], acc[7][r]);
            float pl[4], pr[4];
#pragma unroll
            for (int hh = 0; hh < 4; ++hh) {
                pl[hh] = acc[2 * hh][r] * al[2 * hh] + acc[2 * hh + 1][r] * al[2 * hh + 1];
                pr[hh] = acc[2 * hh][r] * ar[2 * hh] + acc[2 * hh + 1][r] * ar[2 * hh + 1];
            }
#pragma unroll
            for (int o = 1; o < 16; o <<= 1) {
#pragma unroll
                for (int hh = 0; hh < 4; ++hh) {
                    pl[hh] += __shfl_xor(pl[hh], o);
                    pr[hh] += __shfl_xor(pr[hh], o);
                }
            }
            if (row < NN) {
                *(uint4*)(featb + (size_t)row * HD + sub * 8) = fv;
                if (sub < 4) {
                    float vl = (sub == 0) ? pl[0] : (sub == 1) ? pl[1] : (sub == 2) ? pl[2] : pl[3];
                    float vr = (sub == 0) ? pr[0] : (sub == 1) ? pr[1] : (sub == 2) ? pr[2] : pr[3];
                    el[row * 4 + sub] = vl;
                    er[row * 4 + sub] = vr;
                }
            }
        }
    }
}

// ====== D3: build (1024 threads/block): fine histogram -> offs, place ======
__global__ __launch_bounds__(1024) void build_kernel(const unsigned int* __restrict__ pkd,
                                                     const int* __restrict__ regstart,
                                                     int* __restrict__ offs,
                                                     int* __restrict__ csr_src) {
    __shared__ int fcnt[NPB];
    __shared__ int foffs[NPB];
    __shared__ int ssc[NPB];
    int b = blockIdx.x, t = threadIdx.x;     // t < 1024
    int rs = regstart[b], re = regstart[b + 1];
    int n = re - rs;
    if (b == 0 && t == 0) offs[NN] = NE;

    if (t < NPB) fcnt[t] = 0;
    __syncthreads();
    for (int i = t; i < n; i += 1024) {
        unsigned int v = pkd[rs + i];
        atomicAdd(&fcnt[v >> 17], 1);
    }
    __syncthreads();
    // exclusive scan of 512 counts (threads 0..511)
    int a = 0;
    if (t < NPB) { a = fcnt[t]; ssc[t] = a; }
    __syncthreads();
    for (int o = 1; o < NPB; o <<= 1) {
        int u = 0;
        if (t < NPB && t >= o) u = ssc[t - o];
        __syncthreads();
        if (t < NPB) ssc[t] += u;
        __syncthreads();
    }
    if (t < NPB) {
        foffs[t] = ssc[t] - a;
        int node = b * NPB + t;
        if (node < NN) offs[node] = rs + foffs[t];
        fcnt[t] = 0;                         // reuse as cursors
    }
    __syncthreads();
    // placement pass, 4x unrolled, stride 1024
    int i = t;
    for (; i + 3072 < n; i += 4096) {
        unsigned int v0 = pkd[rs + i];
        unsigned int v1 = pkd[rs + i + 1024];
        unsigned int v2 = pkd[rs + i + 2048];
        unsigned int v3 = pkd[rs + i + 3072];
        int j0 = v0 >> 17, j1 = v1 >> 17, j2 = v2 >> 17, j3 = v3 >> 17;
        int r0 = atomicAdd(&fcnt[j0], 1);
        int r1 = atomicAdd(&fcnt[j1], 1);
        int r2 = atomicAdd(&fcnt[j2], 1);
        int r3 = atomicAdd(&fcnt[j3], 1);
        csr_src[rs + foffs[j0] + r0] = (int)(v0 & 0x1FFFFu);
        csr_src[rs + foffs[j1] + r1] = (int)(v1 & 0x1FFFFu);
        csr_src[rs + foffs[j2] + r2] = (int)(v2 & 0x1FFFFu);
        csr_src[rs + foffs[j3] + r3] = (int)(v3 & 0x1FFFFu);
    }
    for (; i < n; i += 1024) {
        unsigned int v = pkd[rs + i];
        int j = v >> 17;
        int r = atomicAdd(&fcnt[j], 1);
        csr_src[rs + foffs[j] + r] = (int)(v & 0x1FFFFu);
    }
}

// ====== D4: softmax + aggregation (at fabric random-gather ceiling) =========
#define CH 32
__global__ __launch_bounds__(256, 4) void aggregate_kernel(const uint4* __restrict__ featu4,
                                                           const float4* __restrict__ el4,
                                                           const float4* __restrict__ er4,
                                                           const int* __restrict__ offs,
                                                           const int* __restrict__ csr_src,
                                                           float* __restrict__ out) {
    __shared__ int    s_sv[4][4][CH + 1];
    __shared__ float4 s_a4[4][4][CH + 1];
    __shared__ int sdeg[16], smap[16];

    const int tid = threadIdx.x;
    const int lane = tid & 63, wv = tid >> 6;
    const int g = lane >> 4, sub = lane & 15;

    // within-block degree sort of the 16 nodes (O(16^2) rank compare)
    if (tid < 16) {
        int n0 = blockIdx.x * 16 + tid;            // NN == 6250*16 exactly
        sdeg[tid] = offs[n0 + 1] - offs[n0];
    }
    __syncthreads();
    if (tid < 16) {
        int d = sdeg[tid];
        int rank = 0;
#pragma unroll
        for (int j = 0; j < 16; ++j) {
            int dj = sdeg[j];
            rank += (dj < d) || (dj == d && j < tid);
        }
        smap[rank] = blockIdx.x * 16 + tid;
    }
    __syncthreads();
    const int node = smap[wv * 4 + g];
    const int beg = offs[node], end = offs[node + 1];

    const float4 erv = er4[node];
    float4 sm = make_float4(0.f, 0.f, 0.f, 0.f);
    f32x2 acc2[4];
#pragma unroll
    for (int i = 0; i < 4; ++i) acc2[i] = (f32x2){0.f, 0.f};

    for (int c0 = beg; c0 < end; c0 += CH) {
        int cnt = end - c0;
        if (cnt > CH) cnt = CH;

        // phase 1: indices -> LDS (pre-scaled by 16 for featu4 addressing)
        int svr[2];
#pragma unroll
        for (int t = 0; t < 2; ++t) {
            int slot = sub + t * 16;
            int sv = (slot < cnt) ? csr_src[c0 + slot] : 0;
            svr[t] = sv;
            s_sv[wv][g][slot] = sv * 16;
        }

        // phase 2: prologue — issue round-0 gather loads now
        uint4 ua[8], ub[8];
#pragma unroll
        for (int e = 0; e < 8; ++e)
            ua[e] = featu4[(size_t)s_sv[wv][g][e] + sub];

        // phase 3: weights (expf chain hides under the round-0 loads)
#pragma unroll
        for (int t = 0; t < 2; ++t) {
            int slot = sub + t * 16;
            float4 w = make_float4(0.f, 0.f, 0.f, 0.f);
            if (slot < cnt) {
                float4 e = el4[svr[t]];
                w.x = __expf(lrelu(e.x + erv.x));
                w.y = __expf(lrelu(e.y + erv.y));
                w.z = __expf(lrelu(e.z + erv.z));
                w.w = __expf(lrelu(e.w + erv.w));
                sm.x += w.x; sm.y += w.y; sm.z += w.z; sm.w += w.w;
            }
            s_a4[wv][g][slot] = w;
        }

        int rounds = (cnt + 7) >> 3;
        int jr = 0;
        while (true) {
            bool m1 = (jr + 1) < rounds;
            if (m1) {
                int nb = (jr + 1) << 3;
#pragma unroll
                for (int e = 0; e < 8; ++e)
                    ub[e] = featu4[(size_t)s_sv[wv][g][nb + e] + sub];
            }
            {
                int jb = jr << 3;
#pragma unroll
                for (int e = 0; e < 8; ++e) {
                    float4 we = s_a4[wv][g][jb + e];
                    uint4 u = ua[e];
                    f32x2 w0 = {we.x, we.x}, w1 = {we.y, we.y};
                    f32x2 w2 = {we.z, we.z}, w3 = {we.w, we.w};
                    acc2[0] = __builtin_elementwise_fma(w0, un2(u.x), acc2[0]);
                    acc2[1] = __builtin_elementwise_fma(w1, un2(u.y), acc2[1]);
                    acc2[2] = __builtin_elementwise_fma(w2, un2(u.z), acc2[2]);
                    acc2[3] = __builtin_elementwise_fma(w3, un2(u.w), acc2[3]);
                }
            }
            ++jr;
            if (!m1) break;
            bool m2 = (jr + 1) < rounds;
            if (m2) {
                int nb = (jr + 1) << 3;
#pragma unroll
                for (int e = 0; e < 8; ++e)
                    ua[e] = featu4[(size_t)s_sv[wv][g][nb + e] + sub];
            }
            {
                int jb = jr << 3;
#pragma unroll
                for (int e = 0; e < 8; ++e) {
                    float4 we = s_a4[wv][g][jb + e];
                    uint4 u = ub[e];
                    f32x2 w0 = {we.x, we.x}, w1 = {we.y, we.y};
                    f32x2 w2 = {we.z, we.z}, w3 = {we.w, we.w};
                    acc2[0] = __builtin_elementwise_fma(w0, un2(u.x), acc2[0]);
                    acc2[1] = __builtin_elementwise_fma(w1, un2(u.y), acc2[1]);
                    acc2[2] = __builtin_elementwise_fma(w2, un2(u.z), acc2[2]);
                    acc2[3] = __builtin_elementwise_fma(w3, un2(u.w), acc2[3]);
                }
            }
            ++jr;
            if (!m2) break;
        }
    }

    // reduce denominators across the 16 lanes of this node
#pragma unroll
    for (int o = 1; o < 16; o <<= 1) {
        sm.x += __shfl_xor(sm.x, o);
        sm.y += __shfl_xor(sm.y, o);
        sm.z += __shfl_xor(sm.z, o);
        sm.w += __shfl_xor(sm.w, o);
    }
    float ix = 1.f / fmaxf(sm.x, 1e-9f);
    float iy = 1.f / fmaxf(sm.y, 1e-9f);
    float iz = 1.f / fmaxf(sm.z, 1e-9f);
    float iw = 1.f / fmaxf(sm.w, 1e-9f);
    float ox = 0.25f * (acc2[0].x * ix + acc2[1].x * iy + acc2[2].x * iz + acc2[3].x * iw);
    float oy = 0.25f * (acc2[0].y * ix + acc2[1].y * iy + acc2[2].y * iz + acc2[3].y * iw);
    out[node * 32 + sub]      = ox;
    out[node * 32 + 16 + sub] = oy;
}

// ---------------- launch ----------------
extern "C" void kernel_launch(void* const* d_in, const int* in_sizes, int n_in,
                              void* d_out, int out_size, void* d_ws, size_t ws_size,
                              hipStream_t stream) {
    const float* x      = (const float*)d_in[0];
    const float* W      = (const float*)d_in[1];
    const float* attn_l = (const float*)d_in[2];
    const float* attn_r = (const float*)d_in[3];
    const int*   src    = (const int*)d_in[4];
    const int*   dst    = (const int*)d_in[5];
    float* out = (float*)d_out;

    char* p = (char*)d_ws;
    auto alloc = [&](size_t bytes) -> void* {
        void* r = (void*)p;
        p += (bytes + 255) & ~(size_t)255;
        return r;
    };
    unsigned short* featb = (unsigned short*)alloc((size_t)NN * HD * 2);
    unsigned int*   wswz  = (unsigned int*)alloc(4096 * 16);
    float* el      = (float*)alloc((size_t)NN * 4 * 4);
    float* er      = (float*)alloc((size_t)NN * 4 * 4);
    int*   offs    = (int*)alloc((size_t)(NN + 1) * 4);
    unsigned int* pkd = (unsigned int*)alloc((size_t)NE * 4);
    int*   csr     = (int*)alloc((size_t)NE * 4);
    int*   gcnt2dT = (int*)alloc((size_t)NB1 * SCP * 4);
    int*   regstart= (int*)alloc((size_t)(NB1 + 1) * 4);

    d1_kernel<<<SC_BLOCKS + 16, 256, 0, stream>>>(W, wswz, (const int4*)dst, gcnt2dT);
    d2_kernel<<<D2_GRID, 256, 0, stream>>>(x, (const uint4*)wswz, attn_l, attn_r,
                                           featb, el, er,
                                           (const int4*)src, (const int4*)dst,
                                           gcnt2dT, pkd, regstart);
    build_kernel<<<NB1, 1024, 0, stream>>>(pkd, regstart, offs, csr);
    aggregate_kernel<<<NN / 16, 256, 0, stream>>>((const uint4*)featb, (const float4*)el,
                                                  (const float4*)er, offs, csr, out);
}